// Round 1
// baseline (680.969 us; speedup 1.0000x reference)
//
#include <hip/hip_runtime.h>

// Problem dims (fixed by reference setup_inputs)
#define BB   2
#define CF_  64
#define CC   3
#define HH   64
#define WW   2048
#define HWs  (HH * WW)      // 131072
#define KK   9
#define CFS  4              // channel splits (threads per pixel-pair)
#define CFT  (CF_ / CFS)    // 16 channels per thread
#define PX   2              // pixels per thread (float2 I/O)

typedef float f2 __attribute__((ext_vector_type(2)));

// out[b, cf*9+n, h, w] = feat[b,cf,h+di,w+dj] * relu(M[cf,:]·rel[:,n])
// M = w1 @ w0  ([64,16]@[16,3] -> [64,3]), rel[c,n] = coordN - center (masked)
// OOB trick: rel[:,n]=0 for invalid taps => wgt=relu(0)=0 => out=0, so feature
// loads can be clamped and unmasked (reference pads features with 0).
__global__ __launch_bounds__(256) void fused_unfold_mlp_kernel(
    const float* __restrict__ feat,
    const float* __restrict__ coord,
    const float* __restrict__ w0,
    const float* __restrict__ w1,
    float* __restrict__ out)
{
    __shared__ float Msh[CFT * CC];   // this block's 16 rows of M = w1@w0 (192 B)

    const int t = threadIdx.x;
    const int p = blockIdx.x * 256 + t;
    // bit layout of p: [q:2][b:1][h:6][w2:10] — h, b, q are block-uniform
    const int q = p >> 17;            // which 16-channel slice

    if (t < CFT * CC) {
        const int o = t / CC, c = t - o * CC;
        const int og = q * CFT + o;
        float acc = 0.f;
#pragma unroll
        for (int k = 0; k < 16; k++)
            acc = fmaf(w1[og * 16 + k], w0[k * CC + c], acc);
        Msh[t] = acc;
    }
    __syncthreads();

    // M is block-uniform: hoist to SGPRs so the hot loop has no LDS reads
    float ms[CFT * CC];
#pragma unroll
    for (int j = 0; j < CFT * CC; j++)
        ms[j] = __uint_as_float(__builtin_amdgcn_readfirstlane(__float_as_uint(Msh[j])));

    const int w2  = p & (WW / 2 - 1);
    const int w0p = w2 * 2;                 // first of 2 pixels
    const int h   = (p >> 10) & (HH - 1);
    const int b   = (p >> 16) & (BB - 1);

    // ---- coord: build rel[px][c][n]; zeroed for invalid taps ----
    const float* __restrict__ cb = coord + (size_t)b * CC * HWs;
    float rel[PX][CC][KK];
#pragma unroll
    for (int px = 0; px < PX; px++) {
        const int w = w0p + px;
        float center[CC];
#pragma unroll
        for (int c = 0; c < CC; c++)
            center[c] = cb[c * HWs + h * WW + w];
#pragma unroll
        for (int n = 0; n < KK; n++) {
            const int di = n / 3 - 1, dj = n % 3 - 1;
            const int hh = h + di, ww = w + dj;
            const bool v = (hh >= 0) && (hh < HH) && (ww >= 0) && (ww < WW);
            const int off = (v ? hh : h) * WW + (v ? ww : w);
#pragma unroll
            for (int c = 0; c < CC; c++) {
                const float r = cb[c * HWs + off] - center[c];
                rel[px][c][n] = (v && center[c] != -1.0f) ? r : 0.0f;
            }
        }
    }

    // ---- clamped feature row/col offsets (unmasked loads are safe) ----
    int rows[3];
    rows[0] = (h > 0      ? h - 1 : 0     ) * WW;
    rows[1] = h * WW;
    rows[2] = (h < HH - 1 ? h + 1 : HH - 1) * WW;
    const int cm1 = (w0p > 0)      ? (w0p - 1) : 0;        // col w0-1 (clamped)
    const int cp2 = (w0p + 2 < WW) ? (w0p + 2) : (WW - 1); // col w0+2 (clamped)

    const float* __restrict__ fb = feat + (size_t)b * CF_ * HWs;
    const int cfbase = q * CFT;
    f2* __restrict__ ob2 = (f2*)(out
        + (size_t)(b * CF_ * KK + cfbase * KK) * HWs + (size_t)h * WW + w0p);

    // 12 unique feature taps per cf: 3 rows x cols {w0-1, w0, w0+1, w0+2}
    auto loadF = [&](float* buf, int cfi) {
        const float* fc = fb + (size_t)(cfbase + cfi) * HWs;
#pragma unroll
        for (int r = 0; r < 3; r++) {
            const float* rp = fc + rows[r];
            buf[r * 4 + 0] = rp[cm1];
            const f2 mid   = *(const f2*)(rp + w0p);   // 8B-aligned (w0p even)
            buf[r * 4 + 1] = mid[0];
            buf[r * 4 + 2] = mid[1];
            buf[r * 4 + 3] = rp[cp2];
        }
    };

    auto computeStore = [&](const float* fv, int i) {
        const float m0 = ms[i * CC + 0], m1 = ms[i * CC + 1], m2 = ms[i * CC + 2];
#pragma unroll
        for (int n = 0; n < KK; n++) {
            const int r = n / 3, j = n % 3;
            float wg0 = fmaf(m2, rel[0][2][n],
                        fmaf(m1, rel[0][1][n], m0 * rel[0][0][n]));
            float wg1 = fmaf(m2, rel[1][2][n],
                        fmaf(m1, rel[1][1][n], m0 * rel[1][0][n]));
            f2 v;
            v[0] = fv[r * 4 + j]     * fmaxf(wg0, 0.f);
            v[1] = fv[r * 4 + j + 1] * fmaxf(wg1, 0.f);
            __builtin_nontemporal_store(v, ob2 + (size_t)(i * KK + n) * (HWs / 2));
        }
    };

    // ---- main loop: prefetch next cf's loads BEFORE issuing this cf's stores,
    // so the in-order vmcnt wait for loads never has to drain pending stores ----
    float fvA[12], fvB[12];
    loadF(fvA, 0);
#pragma unroll
    for (int i = 0; i < CFT; i += 2) {
        loadF(fvB, i + 1);               // prefetch odd channel
        computeStore(fvA, i);            // compute + 9 float2 stores (even)
        if (i + 2 < CFT) loadF(fvA, i + 2);  // prefetch next even channel
        computeStore(fvB, i + 1);        // compute + 9 float2 stores (odd)
    }
}

extern "C" void kernel_launch(void* const* d_in, const int* in_sizes, int n_in,
                              void* d_out, int out_size, void* d_ws, size_t ws_size,
                              hipStream_t stream) {
    const float* feat  = (const float*)d_in[0];
    const float* coord = (const float*)d_in[1];
    const float* w0    = (const float*)d_in[2];
    const float* w1    = (const float*)d_in[3];
    float* out = (float*)d_out;

    // threads = B * H * (W/2) * CFS = 2*64*1024*4 = 524288 -> 2048 blocks
    const int total  = BB * HH * (WW / PX) * CFS;
    const int blocks = total / 256;
    fused_unfold_mlp_kernel<<<blocks, 256, 0, stream>>>(feat, coord, w0, w1, out);
}